// Round 7
// baseline (278.862 us; speedup 1.0000x reference)
//
#include <hip/hip_runtime.h>

#define B_ 16
#define N_ 4096
#define C_ 256
#define K_ 8
#define EPS 1e-6f
#define RATIO 0.1f

typedef float f32x4 __attribute__((ext_vector_type(4)));
typedef __bf16 bf16x8 __attribute__((ext_vector_type(8)));

__device__ inline unsigned short f2bf(float f){
  unsigned int u = __float_as_uint(f);
  u += 0x7FFFu + ((u >> 16) & 1u);   // RNE
  return (unsigned short)(u >> 16);
}
__device__ inline float bf2f(unsigned short h){
  return __uint_as_float(((unsigned int)h) << 16);
}

union BFu { ushort4 u4[2]; bf16x8 v; };

// ---------------- K0: init ws, W1 -> frag-swizzled bf16, Wg hi/lo, geno logits
// W1swz flat index: (((k*16 + nt)*8 + s)*64 + lane)*8 + e
//   holds W1[k][nt*16 + (lane&15)][s*32 + (lane>>4)*8 + e]
__global__ __launch_bounds__(256) void k0_prep(
    const float* __restrict__ W1, const float* __restrict__ Wg,
    const float* __restrict__ geno, const float* __restrict__ Wgg,
    const float* __restrict__ bgg,
    unsigned short* __restrict__ W1swz,
    unsigned short* __restrict__ Wgp_hi, unsigned short* __restrict__ Wgp_lo,
    float* __restrict__ g, int* __restrict__ cnt,
    float* __restrict__ mass, float* __restrict__ conf,
    float* __restrict__ glog)
{
  int gid = blockIdx.x * 256 + threadIdx.x;           // 65536 threads
  if (gid < B_*K_*C_) g[gid] = 0.f;                   // k4 atomics need zeros
  if (gid < B_*K_) { cnt[gid] = 0; mass[gid] = 0.f; }
  if (gid == 0) conf[0] = 0.f;
  {
    int o = gid << 3;                                  // 8 elements per thread
    int lane6 = (o >> 3) & 63;
    int s  = (o >> 9) & 7;
    int nt = (o >> 12) & 15;
    int k  = o >> 16;
    int quad = lane6 >> 4, l16 = lane6 & 15;
    int j  = nt*16 + l16;
    int c0 = s*32 + quad*8;
    const float* src = W1 + (k << 16) + (j << 8) + c0;
    unsigned short* dst = W1swz + o;
    #pragma unroll
    for (int e = 0; e < 8; ++e) dst[e] = f2bf(src[e]);
  }
  if (gid < 16*C_){
    int r = gid >> 8, c = gid & 255;
    float v = (r < K_) ? Wg[(r << 8) + c] : 0.f;
    unsigned short h = f2bf(v);
    Wgp_hi[gid] = h;
    Wgp_lo[gid] = f2bf(v - bf2f(h));
  }
  int wv = gid >> 6;
  if (wv < B_*K_){
    int lane = threadIdx.x & 63;
    int b = wv >> 3, k = wv & 7;
    float4 a = *(const float4*)(geno + b*C_ + lane*4);
    float4 w = *(const float4*)(Wgg  + k*C_ + lane*4);
    float p = a.x*w.x + a.y*w.y + a.z*w.z + a.w*w.w;
    #pragma unroll
    for (int off = 32; off; off >>= 1) p += __shfl_xor(p, off);
    if (lane == 0) glog[wv] = RATIO * (p + bgg[k]);
  }
}

// ---------------- K1: MFMA gate (hi/lo split), top-2, compaction, tok_bf emit
__global__ __launch_bounds__(256) void k1_gate(
    const float* __restrict__ tokens,
    const unsigned short* __restrict__ Wgp_hi, const unsigned short* __restrict__ Wgp_lo,
    const float* __restrict__ bg, const float* __restrict__ glog,
    int* __restrict__ cnt, int* __restrict__ bidx, float* __restrict__ bw,
    float* __restrict__ mass, float* __restrict__ conf,
    unsigned short* __restrict__ tok_bf)
{
  __shared__ float ls[64][9];              // logits, +1 pad
  __shared__ float bg_s[K_], gl_s[K_], mass_s[K_];
  __shared__ int lcnt[K_], gbase[K_];
  __shared__ int e0s[64], e1s[64], s0s[64], s1s[64];
  __shared__ float w0s[64], w1s[64];
  int tid = threadIdx.x, lane = tid & 63, wave = tid >> 6;
  int quad = lane >> 4, l16 = lane & 15;
  int b = blockIdx.x >> 6;
  int tok0 = (blockIdx.x & 63) * 64;
  if (tid < K_){ bg_s[tid] = bg[tid]; gl_s[tid] = glog[b*K_ + tid];
                 mass_s[tid] = 0.f; lcnt[tid] = 0; }
  __syncthreads();

  // phase 1: logits via 3-term split-precision MFMA; emit bf16 tokens
  {
    int trow = tok0 + wave*16 + l16;
    const float* xsrc = tokens + ((size_t)b*N_ + trow)*C_ + quad*8;
    unsigned short* bdst = tok_bf + (((size_t)(b*N_ + trow)) << 8) + quad*8;
    f32x4 acc; acc.x = 0.f; acc.y = 0.f; acc.z = 0.f; acc.w = 0.f;
    #pragma unroll
    for (int s = 0; s < 8; ++s){
      float4 xa = *(const float4*)(xsrc + s*32);
      float4 xb = *(const float4*)(xsrc + s*32 + 4);
      BFu hi, lo;
      hi.u4[0].x = f2bf(xa.x); hi.u4[0].y = f2bf(xa.y);
      hi.u4[0].z = f2bf(xa.z); hi.u4[0].w = f2bf(xa.w);
      hi.u4[1].x = f2bf(xb.x); hi.u4[1].y = f2bf(xb.y);
      hi.u4[1].z = f2bf(xb.z); hi.u4[1].w = f2bf(xb.w);
      lo.u4[0].x = f2bf(xa.x - bf2f(hi.u4[0].x));
      lo.u4[0].y = f2bf(xa.y - bf2f(hi.u4[0].y));
      lo.u4[0].z = f2bf(xa.z - bf2f(hi.u4[0].z));
      lo.u4[0].w = f2bf(xa.w - bf2f(hi.u4[0].w));
      lo.u4[1].x = f2bf(xb.x - bf2f(hi.u4[1].x));
      lo.u4[1].y = f2bf(xb.y - bf2f(hi.u4[1].y));
      lo.u4[1].z = f2bf(xb.z - bf2f(hi.u4[1].z));
      lo.u4[1].w = f2bf(xb.w - bf2f(hi.u4[1].w));
      *(ushort4*)(bdst + s*32)     = hi.u4[0];
      *(ushort4*)(bdst + s*32 + 4) = hi.u4[1];
      bf16x8 bhi = *(const bf16x8*)(Wgp_hi + l16*C_ + s*32 + quad*8);
      bf16x8 blo = *(const bf16x8*)(Wgp_lo + l16*C_ + s*32 + quad*8);
      acc = __builtin_amdgcn_mfma_f32_16x16x32_bf16(hi.v, bhi, acc, 0, 0, 0);
      acc = __builtin_amdgcn_mfma_f32_16x16x32_bf16(lo.v, bhi, acc, 0, 0, 0);
      acc = __builtin_amdgcn_mfma_f32_16x16x32_bf16(hi.v, blo, acc, 0, 0, 0);
    }
    if (l16 < K_){
      #pragma unroll
      for (int rr = 0; rr < 4; ++rr){
        int tl = wave*16 + quad*4 + rr;     // D row = quad*4+reg
        ls[tl][l16] = acc[rr] + bg_s[l16] + gl_s[l16];
      }
    }
  }
  __syncthreads();

  // phase 2: per-token top-2 + softmax + compaction (wave 0 only)
  if (tid < 64){
    int t = tid;
    float v0 = -1e30f, v1 = -1e30f; int i0 = 0, i1 = 0;
    #pragma unroll
    for (int kk = 0; kk < K_; ++kk){
      float l = ls[t][kk];
      if (l > v0){ v1 = v0; i1 = i0; v0 = l; i0 = kk; }
      else if (l > v1){ v1 = l; i1 = kk; }
    }
    float e  = expf(v1 - v0);
    float w0 = 1.f / (1.f + e), w1 = e / (1.f + e);
    w0 = fmaxf(w0, EPS); w1 = fmaxf(w1, EPS);
    float inv = 1.f / (w0 + w1);
    w0 *= inv; w1 *= inv;
    int p0 = atomicAdd(&lcnt[i0], 1);
    int p1 = atomicAdd(&lcnt[i1], 1);
    e0s[t] = i0; e1s[t] = i1; s0s[t] = p0; s1s[t] = p1;
    w0s[t] = w0; w1s[t] = w1;
    atomicAdd(&mass_s[i0], w0);
    atomicAdd(&mass_s[i1], w1);
    float ca = v0 - v1;
    #pragma unroll
    for (int off = 32; off; off >>= 1) ca += __shfl_down(ca, off);
    if (t == 0) atomicAdd(conf, ca);
  }
  __syncthreads();
  if (tid < K_){                            // one global RMW per expert per block
    gbase[tid] = atomicAdd(&cnt[b*K_ + tid], lcnt[tid]);
    atomicAdd(&mass[b*K_ + tid], mass_s[tid]);
  }
  __syncthreads();
  if (tid < 64){
    int t = tid;
    int n = tok0 + t;
    int ke0 = e0s[t], ke1 = e1s[t];
    size_t o0 = (size_t)(b*K_ + ke0)*N_ + gbase[ke0] + s0s[t];
    size_t o1 = (size_t)(b*K_ + ke1)*N_ + gbase[ke1] + s1s[t];
    bidx[o0] = n;  bw[o0] = w0s[t];
    bidx[o1] = n;  bw[o1] = w1s[t];
  }
}

// ---------------- K2: lb_loss + routing confidence ---------------------------
__global__ void k2_scalars(const int* __restrict__ cnt, const float* __restrict__ conf,
                           float* __restrict__ out)
{
  __shared__ int kc[K_];
  int tid = threadIdx.x;
  if (tid < K_) kc[tid] = 0;
  __syncthreads();
  if (tid < B_*K_) atomicAdd(&kc[tid & 7], cnt[tid]);
  __syncthreads();
  if (tid == 0){
    float u[K_], mean = 0.f;
    for (int k = 0; k < K_; ++k){ u[k] = (float)kc[k] / (float)(B_*N_); mean += u[k]; }
    mean *= (1.f / K_);
    float var = 0.f;
    for (int k = 0; k < K_; ++k){ float d = u[k] - mean; var += d*d; }
    var *= (1.f / K_);
    float denom = mean + EPS;
    out[B_*K_*C_]     = var / (denom * denom);
    out[B_*K_*C_ + 1] = conf[0] / (float)(B_*N_);
  }
}

// ---------------- K4: A-in-LDS (gathered once), B streamed from L2 ----------
// grid: x = 128-token chunk (0..31), y = bucket (0..127). block = 256 = 4 waves.
// A staged once in frag order (64 KB LDS); each wave holds its 16 A-frags in
// registers; nt-loop covers ALL 256 j-cols with coalesced L2-resident B loads.
__global__ __launch_bounds__(256, 2) void k4_expert(
    const unsigned short* __restrict__ tok_bf, const unsigned short* __restrict__ W1swz,
    const float* __restrict__ b1, const int* __restrict__ cnt,
    const int* __restrict__ bidx, const float* __restrict__ bw,
    float* __restrict__ g)
{
  int bucket = blockIdx.y;
  int chunk = blockIdx.x;
  int M = cnt[bucket];
  if (chunk * 128 >= M) return;
  int b = bucket >> 3, k = bucket & 7;

  __shared__ unsigned short As[32768];     // 64 KB: [mt(8)][s(8)][lane(64)] x 16B
  __shared__ float gred[4][256];           // 4 KB
  __shared__ float b1s[C_];                // 1 KB
  __shared__ int   ns[128];                // 512 B

  int tid = threadIdx.x, lane = tid & 63, wave = tid >> 6;
  int quad = lane >> 4, l16 = lane & 15;

  b1s[tid] = b1[k*C_ + tid];
  if (tid < 128){
    int r = chunk*128 + tid;
    ns[tid] = (r < M) ? bidx[bucket*N_ + r] : 0;
  }
  __syncthreads();

  // stage A: 128 gathered rows -> frag order. L = ((mt*8+s)*64 + q*16 + l)
  #pragma unroll
  for (int t = 0; t < 16; ++t){
    int L = t*256 + tid;
    int mt = L >> 9, s = (L >> 6) & 7, q = (L >> 4) & 3, l = L & 15;
    int n = ns[mt*16 + l];
    uint4 v = *(const uint4*)(tok_bf + (((size_t)(b*N_ + n)) << 8) + s*32 + q*8);
    *(uint4*)&As[L << 3] = v;
  }
  __syncthreads();

  // each wave: 2 m-tiles (32 tokens); A-frags to registers once
  bf16x8 a[2][8];
  #pragma unroll
  for (int m2 = 0; m2 < 2; ++m2)
    #pragma unroll
    for (int s = 0; s < 8; ++s)
      a[m2][s] = *(const bf16x8*)&As[(((wave*2 + m2)*8 + s)*64 + lane) << 3];

  // routing weights for this wave's 8 C/D rows
  int wr0 = chunk*128 + wave*32 + quad*4;
  int wr1 = wr0 + 16;
  f32x4 wv0 = *(const f32x4*)(bw + bucket*N_ + wr0);
  f32x4 wv1 = *(const f32x4*)(bw + bucket*N_ + wr1);
  f32x4 wq0, wq1;
  #pragma unroll
  for (int rr = 0; rr < 4; ++rr){
    wq0[rr] = (wr0 + rr < M) ? wv0[rr] : 0.f;
    wq1[rr] = (wr1 + rr < M) ? wv1[rr] : 0.f;
  }

  const unsigned short* wb = W1swz + ((size_t)(k*16) << 12);   // nt-tiles of 4096 shorts
  #pragma unroll
  for (int nt = 0; nt < 16; ++nt){
    f32x4 acc0, acc1;
    acc0.x=0.f; acc0.y=0.f; acc0.z=0.f; acc0.w=0.f;
    acc1.x=0.f; acc1.y=0.f; acc1.z=0.f; acc1.w=0.f;
    #pragma unroll
    for (int s = 0; s < 8; ++s){
      bf16x8 bb = *(const bf16x8*)(wb + nt*4096 + s*512 + lane*8);
      acc0 = __builtin_amdgcn_mfma_f32_16x16x32_bf16(a[0][s], bb, acc0, 0,0,0);
      acc1 = __builtin_amdgcn_mfma_f32_16x16x32_bf16(a[1][s], bb, acc1, 0,0,0);
    }
    float bias = b1s[nt*16 + l16];
    float p = 0.f;
    #pragma unroll
    for (int rr = 0; rr < 4; ++rr){
      p += wq0[rr] * fmaxf(acc0[rr] + bias, 0.f);
      p += wq1[rr] * fmaxf(acc1[rr] + bias, 0.f);
    }
    p += __shfl_down(p, 32);
    p += __shfl_down(p, 16);
    if (lane < 16) gred[wave][nt*16 + l16] = p;
  }
  __syncthreads();
  {
    float s = gred[0][tid] + gred[1][tid] + gred[2][tid] + gred[3][tid];
    atomicAdd(&g[bucket*C_ + tid], s);
  }
}

// ---------------- K5: layer-2 on reduced hidden + divide by mass -------------
__global__ __launch_bounds__(256) void k5_centers(
    const float* __restrict__ g, const float* __restrict__ W2,
    const float* __restrict__ b2, const float* __restrict__ mass,
    float* __restrict__ out)
{
  __shared__ float gv[C_];
  int z = blockIdx.x, tid = threadIdx.x;
  int k = z & 7;
  gv[tid] = g[z*C_ + tid];
  __syncthreads();
  float m = mass[z];
  float inv = 1.f / fmaxf(m, EPS);
  int tq = tid & 3, cb = tid >> 2;
  #pragma unroll 1
  for (int h = 0; h < 2; ++h){
    int c = (blockIdx.y*2 + h)*64 + cb;
    const float4* wrow = (const float4*)(W2 + ((((k << 8) + c)) << 8));
    float dot = 0.f;
    #pragma unroll
    for (int jj = 0; jj < 16; ++jj){
      float4 w4 = wrow[jj*4 + tq];
      float4 g4 = *(const float4*)&gv[(jj*4 + tq) * 4];
      dot += w4.x*g4.x + w4.y*g4.y + w4.z*g4.z + w4.w*g4.w;
    }
    dot += __shfl_xor(dot, 1);
    dot += __shfl_xor(dot, 2);
    if (tq == 0) out[z*C_ + c] = (dot + m * b2[k*C_ + c]) * inv;
  }
}

extern "C" void kernel_launch(void* const* d_in, const int* in_sizes, int n_in,
                              void* d_out, int out_size, void* d_ws, size_t ws_size,
                              hipStream_t stream)
{
  const float* tokens = (const float*)d_in[0];
  const float* geno   = (const float*)d_in[1];
  const float* Wg     = (const float*)d_in[2];
  const float* bg     = (const float*)d_in[3];
  const float* Wgg    = (const float*)d_in[4];
  const float* bgg    = (const float*)d_in[5];
  const float* W1     = (const float*)d_in[6];
  const float* b1     = (const float*)d_in[7];
  const float* W2     = (const float*)d_in[8];
  const float* b2     = (const float*)d_in[9];
  float* out = (float*)d_out;
  char* ws = (char*)d_ws;
  unsigned short* W1swz  = (unsigned short*)(ws);              // 1,048,576
  unsigned short* Wgp_hi = (unsigned short*)(ws + 1048576);    //     8,192
  unsigned short* Wgp_lo = (unsigned short*)(ws + 1056768);    //     8,192
  float* g    = (float*)(ws + 1064960);                        //   131,072
  float* glog = (float*)(ws + 1196032);                        //       512
  int*   cnt  = (int*)  (ws + 1196544);                        //       512
  float* mass = (float*)(ws + 1197056);                        //       512
  float* conf = (float*)(ws + 1197568);                        //       512
  int*   bidx = (int*)  (ws + 1198080);                        // 2,097,152
  float* bw   = (float*)(ws + 3295232);                        // 2,097,152
  unsigned short* tok_bf = (unsigned short*)(ws + 5392384);    // 33,554,432

  k0_prep<<<256, 256, 0, stream>>>(W1, Wg, geno, Wgg, bgg, W1swz, Wgp_hi, Wgp_lo,
                                   g, cnt, mass, conf, glog);
  k1_gate<<<1024, 256, 0, stream>>>(tokens, Wgp_hi, Wgp_lo, bg, glog,
                                    cnt, bidx, bw, mass, conf, tok_bf);
  k2_scalars<<<1, 128, 0, stream>>>(cnt, conf, out);
  k4_expert<<<dim3(32, 128), 256, 0, stream>>>(tok_bf, W1swz, b1, cnt, bidx, bw, g);
  k5_centers<<<dim3(128, 2), 256, 0, stream>>>(g, W2, b2, mass, out);
}

// Round 9
// 233.786 us; speedup vs baseline: 1.1928x; 1.1928x over previous
//
#include <hip/hip_runtime.h>

#define B_ 16
#define N_ 4096
#define C_ 256
#define K_ 8
#define EPS 1e-6f
#define RATIO 0.1f

typedef float f32x4 __attribute__((ext_vector_type(4)));
typedef __bf16 bf16x8 __attribute__((ext_vector_type(8)));

__device__ inline unsigned short f2bf(float f){
  unsigned int u = __float_as_uint(f);
  u += 0x7FFFu + ((u >> 16) & 1u);   // RNE
  return (unsigned short)(u >> 16);
}
__device__ inline float bf2f(unsigned short h){
  return __uint_as_float(((unsigned int)h) << 16);
}

union BFu { ushort4 u4[2]; bf16x8 v; };

// ---------------- K0: init ws, W1 -> frag-swizzled bf16, Wg hi/lo, geno logits
// W1swz flat index: (((k*16 + nt)*8 + s)*64 + lane)*8 + e
//   holds W1[k][nt*16 + (lane&15)][s*32 + (lane>>4)*8 + e]
__global__ __launch_bounds__(256) void k0_prep(
    const float* __restrict__ W1, const float* __restrict__ Wg,
    const float* __restrict__ geno, const float* __restrict__ Wgg,
    const float* __restrict__ bgg,
    unsigned short* __restrict__ W1swz,
    unsigned short* __restrict__ Wgp_hi, unsigned short* __restrict__ Wgp_lo,
    float* __restrict__ g, int* __restrict__ cnt,
    float* __restrict__ mass, float* __restrict__ conf,
    float* __restrict__ glog)
{
  int gid = blockIdx.x * 256 + threadIdx.x;           // 65536 threads
  if (gid < B_*K_*C_) g[gid] = 0.f;                   // k4 atomics need zeros
  if (gid < B_*K_) { cnt[gid] = 0; mass[gid] = 0.f; }
  if (gid == 0) conf[0] = 0.f;
  {
    int o = gid << 3;                                  // 8 elements per thread
    int lane6 = (o >> 3) & 63;
    int s  = (o >> 9) & 7;
    int nt = (o >> 12) & 15;
    int k  = o >> 16;
    int quad = lane6 >> 4, l16 = lane6 & 15;
    int j  = nt*16 + l16;
    int c0 = s*32 + quad*8;
    const float* src = W1 + (k << 16) + (j << 8) + c0;
    unsigned short* dst = W1swz + o;
    #pragma unroll
    for (int e = 0; e < 8; ++e) dst[e] = f2bf(src[e]);
  }
  if (gid < 16*C_){
    int r = gid >> 8, c = gid & 255;
    float v = (r < K_) ? Wg[(r << 8) + c] : 0.f;
    unsigned short h = f2bf(v);
    Wgp_hi[gid] = h;
    Wgp_lo[gid] = f2bf(v - bf2f(h));
  }
  int wv = gid >> 6;
  if (wv < B_*K_){
    int lane = threadIdx.x & 63;
    int b = wv >> 3, k = wv & 7;
    float4 a = *(const float4*)(geno + b*C_ + lane*4);
    float4 w = *(const float4*)(Wgg  + k*C_ + lane*4);
    float p = a.x*w.x + a.y*w.y + a.z*w.z + a.w*w.w;
    #pragma unroll
    for (int off = 32; off; off >>= 1) p += __shfl_xor(p, off);
    if (lane == 0) glog[wv] = RATIO * (p + bgg[k]);
  }
}

// ---------------- K1: MFMA gate (hi/lo split), top-2, compaction, tok_bf emit
__global__ __launch_bounds__(256) void k1_gate(
    const float* __restrict__ tokens,
    const unsigned short* __restrict__ Wgp_hi, const unsigned short* __restrict__ Wgp_lo,
    const float* __restrict__ bg, const float* __restrict__ glog,
    int* __restrict__ cnt, int* __restrict__ bidx, float* __restrict__ bw,
    float* __restrict__ mass, float* __restrict__ conf,
    unsigned short* __restrict__ tok_bf)
{
  __shared__ float ls[64][9];              // logits, +1 pad
  __shared__ float bg_s[K_], gl_s[K_], mass_s[K_];
  __shared__ int lcnt[K_], gbase[K_];
  __shared__ int e0s[64], e1s[64], s0s[64], s1s[64];
  __shared__ float w0s[64], w1s[64];
  int tid = threadIdx.x, lane = tid & 63, wave = tid >> 6;
  int quad = lane >> 4, l16 = lane & 15;
  int b = blockIdx.x >> 6;
  int tok0 = (blockIdx.x & 63) * 64;
  if (tid < K_){ bg_s[tid] = bg[tid]; gl_s[tid] = glog[b*K_ + tid];
                 mass_s[tid] = 0.f; lcnt[tid] = 0; }
  __syncthreads();

  // phase 1: logits via 3-term split-precision MFMA; emit bf16 tokens
  {
    int trow = tok0 + wave*16 + l16;
    const float* xsrc = tokens + ((size_t)b*N_ + trow)*C_ + quad*8;
    unsigned short* bdst = tok_bf + (((size_t)(b*N_ + trow)) << 8) + quad*8;
    f32x4 acc; acc.x = 0.f; acc.y = 0.f; acc.z = 0.f; acc.w = 0.f;
    #pragma unroll
    for (int s = 0; s < 8; ++s){
      float4 xa = *(const float4*)(xsrc + s*32);
      float4 xb = *(const float4*)(xsrc + s*32 + 4);
      BFu hi, lo;
      hi.u4[0].x = f2bf(xa.x); hi.u4[0].y = f2bf(xa.y);
      hi.u4[0].z = f2bf(xa.z); hi.u4[0].w = f2bf(xa.w);
      hi.u4[1].x = f2bf(xb.x); hi.u4[1].y = f2bf(xb.y);
      hi.u4[1].z = f2bf(xb.z); hi.u4[1].w = f2bf(xb.w);
      lo.u4[0].x = f2bf(xa.x - bf2f(hi.u4[0].x));
      lo.u4[0].y = f2bf(xa.y - bf2f(hi.u4[0].y));
      lo.u4[0].z = f2bf(xa.z - bf2f(hi.u4[0].z));
      lo.u4[0].w = f2bf(xa.w - bf2f(hi.u4[0].w));
      lo.u4[1].x = f2bf(xb.x - bf2f(hi.u4[1].x));
      lo.u4[1].y = f2bf(xb.y - bf2f(hi.u4[1].y));
      lo.u4[1].z = f2bf(xb.z - bf2f(hi.u4[1].z));
      lo.u4[1].w = f2bf(xb.w - bf2f(hi.u4[1].w));
      *(ushort4*)(bdst + s*32)     = hi.u4[0];
      *(ushort4*)(bdst + s*32 + 4) = hi.u4[1];
      bf16x8 bhi = *(const bf16x8*)(Wgp_hi + l16*C_ + s*32 + quad*8);
      bf16x8 blo = *(const bf16x8*)(Wgp_lo + l16*C_ + s*32 + quad*8);
      acc = __builtin_amdgcn_mfma_f32_16x16x32_bf16(hi.v, bhi, acc, 0, 0, 0);
      acc = __builtin_amdgcn_mfma_f32_16x16x32_bf16(lo.v, bhi, acc, 0, 0, 0);
      acc = __builtin_amdgcn_mfma_f32_16x16x32_bf16(hi.v, blo, acc, 0, 0, 0);
    }
    if (l16 < K_){
      #pragma unroll
      for (int rr = 0; rr < 4; ++rr){
        int tl = wave*16 + quad*4 + rr;     // D row = quad*4+reg
        ls[tl][l16] = acc[rr] + bg_s[l16] + gl_s[l16];
      }
    }
  }
  __syncthreads();

  // phase 2: per-token top-2 + softmax + compaction (wave 0 only)
  if (tid < 64){
    int t = tid;
    float v0 = -1e30f, v1 = -1e30f; int i0 = 0, i1 = 0;
    #pragma unroll
    for (int kk = 0; kk < K_; ++kk){
      float l = ls[t][kk];
      if (l > v0){ v1 = v0; i1 = i0; v0 = l; i0 = kk; }
      else if (l > v1){ v1 = l; i1 = kk; }
    }
    float e  = expf(v1 - v0);
    float w0 = 1.f / (1.f + e), w1 = e / (1.f + e);
    w0 = fmaxf(w0, EPS); w1 = fmaxf(w1, EPS);
    float inv = 1.f / (w0 + w1);
    w0 *= inv; w1 *= inv;
    int p0 = atomicAdd(&lcnt[i0], 1);
    int p1 = atomicAdd(&lcnt[i1], 1);
    e0s[t] = i0; e1s[t] = i1; s0s[t] = p0; s1s[t] = p1;
    w0s[t] = w0; w1s[t] = w1;
    atomicAdd(&mass_s[i0], w0);
    atomicAdd(&mass_s[i1], w1);
    float ca = v0 - v1;
    #pragma unroll
    for (int off = 32; off; off >>= 1) ca += __shfl_down(ca, off);
    if (t == 0) atomicAdd(conf, ca);
  }
  __syncthreads();
  if (tid < K_){                            // one global RMW per expert per block
    gbase[tid] = atomicAdd(&cnt[b*K_ + tid], lcnt[tid]);
    atomicAdd(&mass[b*K_ + tid], mass_s[tid]);
  }
  __syncthreads();
  if (tid < 64){
    int t = tid;
    int n = tok0 + t;
    int ke0 = e0s[t], ke1 = e1s[t];
    size_t o0 = (size_t)(b*K_ + ke0)*N_ + gbase[ke0] + s0s[t];
    size_t o1 = (size_t)(b*K_ + ke1)*N_ + gbase[ke1] + s1s[t];
    bidx[o0] = n;  bw[o0] = w0s[t];
    bidx[o1] = n;  bw[o1] = w1s[t];
  }
}

// ---------------- K2: lb_loss + routing confidence ---------------------------
__global__ void k2_scalars(const int* __restrict__ cnt, const float* __restrict__ conf,
                           float* __restrict__ out)
{
  __shared__ int kc[K_];
  int tid = threadIdx.x;
  if (tid < K_) kc[tid] = 0;
  __syncthreads();
  if (tid < B_*K_) atomicAdd(&kc[tid & 7], cnt[tid]);
  __syncthreads();
  if (tid == 0){
    float u[K_], mean = 0.f;
    for (int k = 0; k < K_; ++k){ u[k] = (float)kc[k] / (float)(B_*N_); mean += u[k]; }
    mean *= (1.f / K_);
    float var = 0.f;
    for (int k = 0; k < K_; ++k){ float d = u[k] - mean; var += d*d; }
    var *= (1.f / K_);
    float denom = mean + EPS;
    out[B_*K_*C_]     = var / (denom * denom);
    out[B_*K_*C_ + 1] = conf[0] / (float)(B_*N_);
  }
}

// ---------------- K4 (R4-proven): A-in-registers, B staged via global_load_lds
// grid: x = 128-token chunk (0..31), y = bucket (0..127). block = 256 = 4 waves.
// A frags gathered once per block (reused across 4 jt); W1swz jt-quarter (32 KB)
// staged to LDS contiguously; frag reads = ds_read_b128 base+lane*16.
__global__ __launch_bounds__(256, 3) void k4_expert(
    const unsigned short* __restrict__ tok_bf, const unsigned short* __restrict__ W1swz,
    const float* __restrict__ b1, const int* __restrict__ cnt,
    const int* __restrict__ bidx, const float* __restrict__ bw,
    float* __restrict__ g)
{
  int bucket = blockIdx.y;
  int M = cnt[bucket];
  int chunk = blockIdx.x;
  if (chunk * 128 >= M) return;
  int b = bucket >> 3, k = bucket & 7;

  __shared__ unsigned short Bs[16384];     // 32 KB: one jt quarter in frag order
  __shared__ float wtok[128];
  __shared__ float b1s[C_];

  int tid = threadIdx.x, lane = tid & 63, wave = tid >> 6;
  int quad = lane >> 4, l16 = lane & 15;
  if (tid < 128){
    int tn = chunk*128 + tid;
    wtok[tid] = (tn < M) ? bw[bucket*N_ + tn] : 0.f;
  }
  b1s[tid] = b1[k*C_ + tid];

  // gather A fragments once; held in registers across all jt
  int r0 = chunk*128 + wave*16 + l16;
  int r1 = r0 + 64;
  int n0 = (r0 < M) ? bidx[bucket*N_ + r0] : 0;
  int n1 = (r1 < M) ? bidx[bucket*N_ + r1] : 0;
  const unsigned short* pa0 = tok_bf + (((size_t)(b*N_ + n0)) << 8) + quad*8;
  const unsigned short* pa1 = tok_bf + (((size_t)(b*N_ + n1)) << 8) + quad*8;
  bf16x8 a0[8], a1[8];
  #pragma unroll
  for (int s = 0; s < 8; ++s){
    a0[s] = *(const bf16x8*)(pa0 + s*32);
    a1[s] = *(const bf16x8*)(pa1 + s*32);
  }

  const unsigned short* wsrc = W1swz + ((k*4) << 14);   // + jt*16384

  #pragma unroll 1
  for (int jt = 0; jt < 4; ++jt){
    __syncthreads();                       // Bs safe to overwrite
    #pragma unroll
    for (int i = 0; i < 8; ++i){
      int c16 = i*256 + tid;               // 16-byte chunk index within tile
      __builtin_amdgcn_global_load_lds(
        (const __attribute__((address_space(1))) unsigned int*)(wsrc + jt*16384 + c16*8),
        (__attribute__((address_space(3))) unsigned int*)(Bs + c16*8), 16, 0, 0);
    }
    __syncthreads();                       // compiler drains vmcnt before barrier

    f32x4 acc[2][4];
    #pragma unroll
    for (int mt = 0; mt < 2; ++mt)
      #pragma unroll
      for (int t = 0; t < 4; ++t){ acc[mt][t].x=0.f; acc[mt][t].y=0.f; acc[mt][t].z=0.f; acc[mt][t].w=0.f; }
    #pragma unroll
    for (int s = 0; s < 8; ++s){
      #pragma unroll
      for (int t = 0; t < 4; ++t){
        bf16x8 bb = *(const bf16x8*)(Bs + (((t*8 + s)*64 + lane) << 3));
        acc[0][t] = __builtin_amdgcn_mfma_f32_16x16x32_bf16(a0[s], bb, acc[0][t], 0,0,0);
        acc[1][t] = __builtin_amdgcn_mfma_f32_16x16x32_bf16(a1[s], bb, acc[1][t], 0,0,0);
      }
    }
    #pragma unroll
    for (int t = 0; t < 4; ++t){
      float bias = b1s[jt*64 + t*16 + l16];
      float pt = 0.f;
      #pragma unroll
      for (int mt = 0; mt < 2; ++mt){
        #pragma unroll
        for (int rr = 0; rr < 4; ++rr){
          float h = acc[mt][t][rr] + bias;
          h = fmaxf(h, 0.f);
          pt += wtok[mt*64 + wave*16 + quad*4 + rr] * h;
        }
      }
      pt += __shfl_down(pt, 32);
      pt += __shfl_down(pt, 16);
      if (lane < 16) atomicAdd(&g[bucket*C_ + jt*64 + t*16 + lane], pt);
    }
  }
}

// ---------------- K5 (R7-proven): layer-2 on reduced hidden + divide by mass -
__global__ __launch_bounds__(256) void k5_centers(
    const float* __restrict__ g, const float* __restrict__ W2,
    const float* __restrict__ b2, const float* __restrict__ mass,
    float* __restrict__ out)
{
  __shared__ float gv[C_];
  int z = blockIdx.x, tid = threadIdx.x;
  int k = z & 7;
  gv[tid] = g[z*C_ + tid];
  __syncthreads();
  float m = mass[z];
  float inv = 1.f / fmaxf(m, EPS);
  int tq = tid & 3, cb = tid >> 2;
  #pragma unroll 1
  for (int h = 0; h < 2; ++h){
    int c = (blockIdx.y*2 + h)*64 + cb;
    const float4* wrow = (const float4*)(W2 + ((((k << 8) + c)) << 8));
    float dot = 0.f;
    #pragma unroll
    for (int jj = 0; jj < 16; ++jj){
      float4 w4 = wrow[jj*4 + tq];
      float4 g4 = *(const float4*)&gv[(jj*4 + tq) * 4];
      dot += w4.x*g4.x + w4.y*g4.y + w4.z*g4.z + w4.w*g4.w;
    }
    dot += __shfl_xor(dot, 1);
    dot += __shfl_xor(dot, 2);
    if (tq == 0) out[z*C_ + c] = (dot + m * b2[k*C_ + c]) * inv;
  }
}

extern "C" void kernel_launch(void* const* d_in, const int* in_sizes, int n_in,
                              void* d_out, int out_size, void* d_ws, size_t ws_size,
                              hipStream_t stream)
{
  const float* tokens = (const float*)d_in[0];
  const float* geno   = (const float*)d_in[1];
  const float* Wg     = (const float*)d_in[2];
  const float* bg     = (const float*)d_in[3];
  const float* Wgg    = (const float*)d_in[4];
  const float* bgg    = (const float*)d_in[5];
  const float* W1     = (const float*)d_in[6];
  const float* b1     = (const float*)d_in[7];
  const float* W2     = (const float*)d_in[8];
  const float* b2     = (const float*)d_in[9];
  float* out = (float*)d_out;
  char* ws = (char*)d_ws;
  unsigned short* W1swz  = (unsigned short*)(ws);              // 1,048,576
  unsigned short* Wgp_hi = (unsigned short*)(ws + 1048576);    //     8,192
  unsigned short* Wgp_lo = (unsigned short*)(ws + 1056768);    //     8,192
  float* g    = (float*)(ws + 1064960);                        //   131,072
  float* glog = (float*)(ws + 1196032);                        //       512
  int*   cnt  = (int*)  (ws + 1196544);                        //       512
  float* mass = (float*)(ws + 1197056);                        //       512
  float* conf = (float*)(ws + 1197568);                        //       512
  int*   bidx = (int*)  (ws + 1198080);                        // 2,097,152
  float* bw   = (float*)(ws + 3295232);                        // 2,097,152
  unsigned short* tok_bf = (unsigned short*)(ws + 5392384);    // 33,554,432

  k0_prep<<<256, 256, 0, stream>>>(W1, Wg, geno, Wgg, bgg, W1swz, Wgp_hi, Wgp_lo,
                                   g, cnt, mass, conf, glog);
  k1_gate<<<1024, 256, 0, stream>>>(tokens, Wgp_hi, Wgp_lo, bg, glog,
                                    cnt, bidx, bw, mass, conf, tok_bf);
  k2_scalars<<<1, 128, 0, stream>>>(cnt, conf, out);
  k4_expert<<<dim3(32, 128), 256, 0, stream>>>(tok_bf, W1swz, b1, cnt, bidx, bw, g);
  k5_centers<<<dim3(128, 2), 256, 0, stream>>>(g, W2, b2, mass, out);
}